// Round 5
// baseline (188.931 us; speedup 1.0000x reference)
//
#include <hip/hip_runtime.h>
#include <math.h>

#define B_   2
#define L1_  4096
#define L2_  6144
#define DM_  256
#define H_   8
#define DH_  32

typedef __bf16 bf16x8 __attribute__((ext_vector_type(8)));
typedef __bf16 bf16x4 __attribute__((ext_vector_type(4)));
typedef float floatx4 __attribute__((ext_vector_type(4)));

__device__ __forceinline__ bf16x8 ldb(const __bf16* p) { return *(const bf16x8*)p; }

__device__ __forceinline__ bf16x4 pack4(floatx4 v) {
    bf16x4 r;
    r[0] = (__bf16)v[0]; r[1] = (__bf16)v[1];
    r[2] = (__bf16)v[2]; r[3] = (__bf16)v[3];
    return r;
}

// ---- convert W (qscale folded into Wq), x, source to bf16. Pure bandwidth. ----
// float4 units: W = 3*16384 = 49152, x = 524288, src = 786432; total 1359872 = 5312*256
__global__ __launch_bounds__(256) void cvt_all(
    const float* __restrict__ wq, const float* __restrict__ wk,
    const float* __restrict__ wv, const float* __restrict__ x,
    const float* __restrict__ src,
    __bf16* __restrict__ wbf, __bf16* __restrict__ xbf, __bf16* __restrict__ sbf,
    float qscale)
{
    int i = blockIdx.x * 256 + threadIdx.x;
    const float* s; __bf16* d; float sc = 1.0f; size_t off;
    if (i < 49152) {
        int seg = i >> 14;
        off = (size_t)(i & 16383) * 4;
        s = seg == 0 ? wq : (seg == 1 ? wk : wv);
        d = wbf + (size_t)seg * 65536;
        if (seg == 0) sc = qscale;
    } else if (i < 49152 + 524288) {
        off = (size_t)(i - 49152) * 4; s = x; d = xbf;
    } else {
        off = (size_t)(i - 49152 - 524288) * 4; s = src; d = sbf;
    }
    float4 v = *(const float4*)(s + off);
    bf16x4 r;
    r[0] = (__bf16)(v.x * sc); r[1] = (__bf16)(v.y * sc);
    r[2] = (__bf16)(v.z * sc); r[3] = (__bf16)(v.w * sc);
    *(bf16x4*)(d + off) = r;
}

// ---- proj v3: all-bf16 GEMM. Block = 32 rows x 256 cols, wave = 32x64.
// 1D grid 1024: [0,256)=Q, [256,640)=K, [640,1024)=V. Zero VALU in K-loop.
// Q/K transposed orientation (d in regs -> 8B stores); V normal + LDS transpose
// so VT gets full-line 16B stores.
__global__ __launch_bounds__(256) void proj_kernel(
    const __bf16* __restrict__ xbf, const __bf16* __restrict__ sbf,
    const __bf16* __restrict__ Wbf,
    __bf16* __restrict__ qo, __bf16* __restrict__ ko, __bf16* __restrict__ vo)
{
    __shared__ __bf16 ldsV[256 * 36];   // 18 KB, used only by V blocks (pad 32->36)

    const int bid = blockIdx.x;
    int y, xb;
    if      (bid < 256) { y = 0; xb = bid; }
    else if (bid < 640) { y = 1; xb = bid - 256; }
    else                { y = 2; xb = bid - 640; }

    const int L = (y == 0) ? L1_ : L2_;
    const __bf16* X   = (y == 0) ? xbf : sbf;
    const __bf16* Wb  = Wbf + (size_t)y * 65536;
    __bf16*       out = (y == 0) ? qo : (y == 1 ? ko : vo);

    const int lane = threadIdx.x & 63;
    const int w    = threadIdx.x >> 6;   // 64-col strip
    const int g    = lane >> 4;
    const int c    = lane & 15;
    const int mb   = xb * 32;
    const int b    = mb / L;
    const int lb   = mb - b * L;

    floatx4 acc[2][4];
#pragma unroll
    for (int s = 0; s < 2; s++)
#pragma unroll
        for (int n = 0; n < 4; n++) acc[s][n] = (floatx4){0.f, 0.f, 0.f, 0.f};

#pragma unroll
    for (int kc = 0; kc < 8; kc++) {
        bf16x8 xf0 = ldb(X + (size_t)(mb + c) * DM_ + kc * 32 + g * 8);
        bf16x8 xf1 = ldb(X + (size_t)(mb + 16 + c) * DM_ + kc * 32 + g * 8);
#pragma unroll
        for (int n = 0; n < 4; n++) {
            const int oc = w * 64 + n * 16 + c;
            bf16x8 wf = ldb(Wb + (size_t)oc * DM_ + kc * 32 + g * 8);
            if (y == 2) {   // V normal: rows (regs) = l
                acc[0][n] = __builtin_amdgcn_mfma_f32_16x16x32_bf16(xf0, wf, acc[0][n], 0, 0, 0);
                acc[1][n] = __builtin_amdgcn_mfma_f32_16x16x32_bf16(xf1, wf, acc[1][n], 0, 0, 0);
            } else {        // Q/K transposed: rows (regs) = oc
                acc[0][n] = __builtin_amdgcn_mfma_f32_16x16x32_bf16(wf, xf0, acc[0][n], 0, 0, 0);
                acc[1][n] = __builtin_amdgcn_mfma_f32_16x16x32_bf16(wf, xf1, acc[1][n], 0, 0, 0);
            }
        }
    }

    const int bhb = b * H_;
    if (y == 2) {
        // stage tile [d_global 0..255][l_local 0..31] in LDS (pad 36), then
        // one thread per d-row writes a full 64B line of VT.
#pragma unroll
        for (int s = 0; s < 2; s++)
#pragma unroll
            for (int n = 0; n < 4; n++) {
                int dg = w * 64 + (n >> 1) * 32 + (n & 1) * 16 + c;   // h*32+d
                int ll = s * 16 + g * 4;
                *(bf16x4*)(ldsV + (size_t)dg * 36 + ll) = pack4(acc[s][n]);
            }
        __syncthreads();
        const int t = threadIdx.x;           // d_global row
        const int h = t >> 5, d = t & 31;
        __bf16* row = out + ((size_t)(bhb + h) * DH_ + d) * (size_t)L + lb;
#pragma unroll
        for (int j = 0; j < 4; j++)
            *(bf16x8*)(row + j * 8) = *(const bf16x8*)(ldsV + (size_t)t * 36 + j * 8);
    } else {
        // QK[(bh*L + l)*32 + d], d = (n&1)*16 + g*4 + r (regs), l = lb + s*16 + c (lanes)
#pragma unroll
        for (int s = 0; s < 2; s++)
#pragma unroll
            for (int n = 0; n < 4; n++) {
                int dlo = (n & 1) * 16 + g * 4;
                int h = w * 2 + (n >> 1);
                int l = lb + s * 16 + c;
                *(bf16x4*)(out + ((size_t)(bhb + h) * (size_t)L + l) * DH_ + dlo) = pack4(acc[s][n]);
            }
    }
}

// ---- flash attention: 64 q/wave, K reg-dbuf, split-K over L2, XCD-swizzled grid ----
__device__ __forceinline__ void attn_step(
    const bf16x8 (&qf)[4], const bf16x8 (&kf)[4], bf16x8 (&kfN)[4],
    const __bf16* __restrict__ knext,
    const __bf16* __restrict__ vb0, const __bf16* __restrict__ vb1, int kb,
    __bf16* __restrict__ Pw, int g, int c,
    float (&l)[4], floatx4 (&o)[4][2])
{
    bf16x8 vf0 = ldb(vb0 + kb);
    bf16x8 vf1 = ldb(vb1 + kb);
    bf16x8 vf2 = ldb(vb0 + kb + 32);
    bf16x8 vf3 = ldb(vb1 + kb + 32);
    kfN[0] = ldb(knext);
    kfN[1] = ldb(knext + 16 * DH_);
    kfN[2] = ldb(knext + 32 * DH_);
    kfN[3] = ldb(knext + 48 * DH_);

#pragma unroll
    for (int h = 0; h < 4; h++) {
        floatx4 s[4];
#pragma unroll
        for (int st = 0; st < 4; st++)
            s[st] = __builtin_amdgcn_mfma_f32_16x16x32_bf16(
                        kf[st], qf[h], (floatx4){0.f, 0.f, 0.f, 0.f}, 0, 0, 0);
#pragma unroll
        for (int st = 0; st < 4; st++) {
            float a0 = __builtin_amdgcn_exp2f(s[st][0]);
            float a1 = __builtin_amdgcn_exp2f(s[st][1]);
            float a2 = __builtin_amdgcn_exp2f(s[st][2]);
            float a3 = __builtin_amdgcn_exp2f(s[st][3]);
            l[h] += (a0 + a1) + (a2 + a3);
            bf16x4 pk;
            pk[0] = (__bf16)a0; pk[1] = (__bf16)a1;
            pk[2] = (__bf16)a2; pk[3] = (__bf16)a3;
            *(bf16x4*)(Pw + h * 1024 + ((st * 2 + (g >> 1)) * 16 + c) * 8 + (g & 1) * 4) = pk;
        }
    }

#pragma unroll
    for (int kc = 0; kc < 2; kc++) {
#pragma unroll
        for (int h = 0; h < 4; h++) {
            bf16x8 pa = *(const bf16x8*)(Pw + h * 1024 + ((kc * 4 + g) * 16 + c) * 8);
            o[h][0] = __builtin_amdgcn_mfma_f32_16x16x32_bf16(pa, kc ? vf2 : vf0, o[h][0], 0, 0, 0);
            o[h][1] = __builtin_amdgcn_mfma_f32_16x16x32_bf16(pa, kc ? vf3 : vf1, o[h][1], 0, 0, 0);
        }
    }
}

template<bool DIRECT>
__global__ __launch_bounds__(256, 2) void attn_kernel(
    const __bf16* __restrict__ Q, const __bf16* __restrict__ K,
    const __bf16* __restrict__ VT, float* __restrict__ out,
    float* __restrict__ Opart, float* __restrict__ Lpart, int klen, int split)
{
    __shared__ __bf16 ldsP[4][4][1024];   // [wave][q-group], wave-private, 32 KB

    // XCD swizzle: each XCD (bid%8) owns a contiguous range of work -> the
    // 16 q-blocks sharing one (bh,z) K/V slice (192 KB) stay in one XCD L2.
    const int bid  = blockIdx.x;
    const int work = (bid & 7) * (32 * split) + (bid >> 3);
    const int xb   = work & 15;
    const int bh   = (work >> 4) & 15;
    const int z    = work >> 8;

    const int lane  = threadIdx.x & 63;
    const int w     = threadIdx.x >> 6;
    const int g     = lane >> 4;
    const int c     = lane & 15;
    const int qbase = xb * 256 + w * 64;
    const int k0    = z * klen;

    bf16x8 qf[4];
#pragma unroll
    for (int h = 0; h < 4; h++)
        qf[h] = ldb(Q + ((size_t)bh * L1_ + qbase + h * 16 + c) * DH_ + g * 8);

    const __bf16* kbase = K  + (size_t)bh * L2_ * DH_ + (size_t)c * DH_ + g * 8;
    const __bf16* vb0   = VT + ((size_t)bh * DH_ + c)      * L2_ + g * 8;
    const __bf16* vb1   = VT + ((size_t)bh * DH_ + 16 + c) * L2_ + g * 8;
    __bf16* Pw = &ldsP[w][0][0];

    float l[4] = {0.f, 0.f, 0.f, 0.f};
    floatx4 o[4][2];
#pragma unroll
    for (int h = 0; h < 4; h++) { o[h][0] = (floatx4){0.f,0.f,0.f,0.f}; o[h][1] = (floatx4){0.f,0.f,0.f,0.f}; }

    bf16x8 kfA[4], kfB[4];
#pragma unroll
    for (int st = 0; st < 4; st++)
        kfA[st] = ldb(kbase + (size_t)(k0 + st * 16) * DH_);

    for (int t = 0; t < klen; t += 128) {
        int kb = k0 + t;
        attn_step(qf, kfA, kfB, kbase + (size_t)(kb + 64) * DH_,
                  vb0, vb1, kb, Pw, g, c, l, o);
        int nn = (t + 128 < klen) ? kb + 128 : k0;
        attn_step(qf, kfB, kfA, kbase + (size_t)nn * DH_,
                  vb0, vb1, kb + 64, Pw, g, c, l, o);
    }

#pragma unroll
    for (int h = 0; h < 4; h++) {
        l[h] += __shfl_xor(l[h], 16, 64);
        l[h] += __shfl_xor(l[h], 32, 64);
    }

    const int b  = bh / H_;
    const int hh = bh % H_;
    if (DIRECT) {
#pragma unroll
        for (int h = 0; h < 4; h++)
#pragma unroll
            for (int r = 0; r < 4; r++) {
                float lr  = __shfl(l[h], g * 4 + r, 64);
                float inv = 1.0f / lr;
                size_t base = ((size_t)(b * L1_ + qbase + h * 16 + g * 4 + r)) * DM_ + hh * DH_;
                out[base + c]      = o[h][0][r] * inv;
                out[base + 16 + c] = o[h][1][r] * inv;
            }
    } else {
        float* Op = Opart + (size_t)z * ((size_t)B_ * L1_ * DM_);
#pragma unroll
        for (int h = 0; h < 4; h++) {
#pragma unroll
            for (int r = 0; r < 4; r++) {
                size_t base = ((size_t)(b * L1_ + qbase + h * 16 + g * 4 + r)) * DM_ + hh * DH_;
                Op[base + c]      = o[h][0][r];
                Op[base + 16 + c] = o[h][1][r];
            }
            if (g == 0)
                Lpart[(size_t)z * ((size_t)B_ * H_ * L1_) +
                      (size_t)bh * L1_ + qbase + h * 16 + c] = l[h];
        }
    }
}

// out = (sum_z Opart) / (sum_z Lpart); 524288 threads, float4 each.
__global__ __launch_bounds__(256) void combine_kernel(
    const float* __restrict__ Opart, const float* __restrict__ Lpart,
    float* __restrict__ out, int split)
{
    int t   = blockIdx.x * 256 + threadIdx.x;
    int row = t >> 6;             // b*L1 + q
    int col = (t & 63) * 4;       // dm
    int b   = row >> 12;
    int q   = row & (L1_ - 1);
    int bh  = b * H_ + (col >> 5);
    float4 a = {0.f, 0.f, 0.f, 0.f};
    float ls = 0.f;
    for (int z = 0; z < split; z++) {
        const float* Op = Opart + (size_t)z * ((size_t)B_ * L1_ * DM_);
        float4 v = *(const float4*)(Op + (size_t)row * DM_ + col);
        a.x += v.x; a.y += v.y; a.z += v.z; a.w += v.w;
        ls += Lpart[(size_t)z * ((size_t)B_ * H_ * L1_) + (size_t)bh * L1_ + q];
    }
    float inv = 1.0f / ls;
    float4 r; r.x = a.x * inv; r.y = a.y * inv; r.z = a.z * inv; r.w = a.w * inv;
    *(float4*)(out + (size_t)row * DM_ + col) = r;
}

extern "C" void kernel_launch(void* const* d_in, const int* in_sizes, int n_in,
                              void* d_out, int out_size, void* d_ws, size_t ws_size,
                              hipStream_t stream) {
    const float* x   = (const float*)d_in[0];
    const float* src = (const float*)d_in[1];
    const float* Wq  = (const float*)d_in[2];
    const float* Wk  = (const float*)d_in[3];
    const float* Wv  = (const float*)d_in[4];
    float* out = (float*)d_out;

    const float qscale = 1.4426950408889634f / sqrtf((float)DH_); // log2e * Dh^-0.5

    const size_t nW = 3 * 65536;                     //   196,608
    const size_t nQ = (size_t)B_ * H_ * L1_ * DH_;   // 2,097,152
    const size_t nK = (size_t)B_ * H_ * L2_ * DH_;   // 3,145,728
    const size_t nX = nQ;                            // x bf16
    const size_t nS = nK;                            // source bf16

    // persistent: [W | Q | K | VT], then a union region:
    //   phase 1 (cvt+proj): xbf, sbf      phase 2 (attn+combine): Opart, Lpart
    __bf16* wbf = (__bf16*)d_ws;
    __bf16* qws = wbf + nW;
    __bf16* kws = qws + nQ;
    __bf16* vt  = kws + nK;
    size_t unionOff = ((nW + nQ + 2 * nK) * sizeof(__bf16) + 255) & ~(size_t)255;
    __bf16* xbf = (__bf16*)((char*)d_ws + unionOff);
    __bf16* sbf = xbf + nX;

    const size_t oPartB = (size_t)B_ * L1_ * DM_ * 4;     // 8 MB per split
    const size_t lPartB = (size_t)B_ * H_ * L1_ * 4;      // 256 KB per split
    const size_t avail  = ws_size > unionOff ? ws_size - unionOff : 0;
    int split = 1;
    if      (avail >= 4 * (oPartB + lPartB)) split = 4;
    else if (avail >= 2 * (oPartB + lPartB)) split = 2;
    float* Opart = (float*)((char*)d_ws + unionOff);
    float* Lpart = (float*)((char*)d_ws + unionOff + (size_t)split * oPartB);

    cvt_all<<<dim3(5312), 256, 0, stream>>>(Wq, Wk, Wv, x, src, wbf, xbf, sbf, qscale);
    proj_kernel<<<dim3(1024), 256, 0, stream>>>(xbf, sbf, wbf, qws, kws, vt);

    if (split > 1) {
        attn_kernel<false><<<dim3(256 * split), 256, 0, stream>>>(
            qws, kws, vt, nullptr, Opart, Lpart, L2_ / split, split);
        combine_kernel<<<dim3(2048), 256, 0, stream>>>(Opart, Lpart, out, split);
    } else {
        attn_kernel<true><<<dim3(256), 256, 0, stream>>>(
            qws, kws, vt, out, nullptr, nullptr, L2_, 1);
    }
}

// Round 7
// 188.847 us; speedup vs baseline: 1.0004x; 1.0004x over previous
//
#include <hip/hip_runtime.h>
#include <math.h>

#define B_   2
#define L1_  4096
#define L2_  6144
#define DM_  256
#define H_   8
#define DH_  32

typedef __bf16 bf16x8 __attribute__((ext_vector_type(8)));
typedef __bf16 bf16x4 __attribute__((ext_vector_type(4)));
typedef float floatx4 __attribute__((ext_vector_type(4)));
typedef _Float16 f16;
typedef _Float16 f16x4 __attribute__((ext_vector_type(4)));
typedef _Float16 f16x8 __attribute__((ext_vector_type(8)));
typedef __fp16 fp16v2 __attribute__((ext_vector_type(2)));   // cvt_pkrtz return type

__device__ __forceinline__ bf16x8 ldb(const __bf16* p) { return *(const bf16x8*)p; }

__device__ __forceinline__ bf16x4 pack4(floatx4 v) {
    bf16x4 r;
    r[0] = (__bf16)v[0]; r[1] = (__bf16)v[1];
    r[2] = (__bf16)v[2]; r[3] = (__bf16)v[3];
    return r;
}

__device__ __forceinline__ float pkrtz(float a, float b) {
    fp16v2 p = __builtin_amdgcn_cvt_pkrtz(a, b);
    return __builtin_bit_cast(float, p);
}

// ---- convert W (qscale folded into Wq), x, source to bf16. Pure bandwidth. ----
__global__ __launch_bounds__(256) void cvt_all(
    const float* __restrict__ wq, const float* __restrict__ wk,
    const float* __restrict__ wv, const float* __restrict__ x,
    const float* __restrict__ src,
    __bf16* __restrict__ wbf, __bf16* __restrict__ xbf, __bf16* __restrict__ sbf,
    float qscale)
{
    int i = blockIdx.x * 256 + threadIdx.x;
    const float* s; __bf16* d; float sc = 1.0f; size_t off;
    if (i < 49152) {
        int seg = i >> 14;
        off = (size_t)(i & 16383) * 4;
        s = seg == 0 ? wq : (seg == 1 ? wk : wv);
        d = wbf + (size_t)seg * 65536;
        if (seg == 0) sc = qscale;
    } else if (i < 49152 + 524288) {
        off = (size_t)(i - 49152) * 4; s = x; d = xbf;
    } else {
        off = (size_t)(i - 49152 - 524288) * 4; s = src; d = sbf;
    }
    float4 v = *(const float4*)(s + off);
    bf16x4 r;
    r[0] = (__bf16)(v.x * sc); r[1] = (__bf16)(v.y * sc);
    r[2] = (__bf16)(v.z * sc); r[3] = (__bf16)(v.w * sc);
    *(bf16x4*)(d + off) = r;
}

// ---- proj: all-bf16 GEMM; Q/K out bf16, V out fp16 (transposed via LDS). ----
__global__ __launch_bounds__(256) void proj_kernel(
    const __bf16* __restrict__ xbf, const __bf16* __restrict__ sbf,
    const __bf16* __restrict__ Wbf,
    __bf16* __restrict__ qo, __bf16* __restrict__ ko, f16* __restrict__ vo)
{
    __shared__ f16 ldsV[256 * 36];   // 18 KB, V blocks only

    const int bid = blockIdx.x;
    int y, xb;
    if      (bid < 256) { y = 0; xb = bid; }
    else if (bid < 640) { y = 1; xb = bid - 256; }
    else                { y = 2; xb = bid - 640; }

    const int L = (y == 0) ? L1_ : L2_;
    const __bf16* X   = (y == 0) ? xbf : sbf;
    const __bf16* Wb  = Wbf + (size_t)y * 65536;

    const int lane = threadIdx.x & 63;
    const int w    = threadIdx.x >> 6;
    const int g    = lane >> 4;
    const int c    = lane & 15;
    const int mb   = xb * 32;
    const int b    = mb / L;
    const int lb   = mb - b * L;

    floatx4 acc[2][4];
#pragma unroll
    for (int s = 0; s < 2; s++)
#pragma unroll
        for (int n = 0; n < 4; n++) acc[s][n] = (floatx4){0.f, 0.f, 0.f, 0.f};

#pragma unroll
    for (int kc = 0; kc < 8; kc++) {
        bf16x8 xf0 = ldb(X + (size_t)(mb + c) * DM_ + kc * 32 + g * 8);
        bf16x8 xf1 = ldb(X + (size_t)(mb + 16 + c) * DM_ + kc * 32 + g * 8);
#pragma unroll
        for (int n = 0; n < 4; n++) {
            const int oc = w * 64 + n * 16 + c;
            bf16x8 wf = ldb(Wb + (size_t)oc * DM_ + kc * 32 + g * 8);
            if (y == 2) {
                acc[0][n] = __builtin_amdgcn_mfma_f32_16x16x32_bf16(xf0, wf, acc[0][n], 0, 0, 0);
                acc[1][n] = __builtin_amdgcn_mfma_f32_16x16x32_bf16(xf1, wf, acc[1][n], 0, 0, 0);
            } else {
                acc[0][n] = __builtin_amdgcn_mfma_f32_16x16x32_bf16(wf, xf0, acc[0][n], 0, 0, 0);
                acc[1][n] = __builtin_amdgcn_mfma_f32_16x16x32_bf16(wf, xf1, acc[1][n], 0, 0, 0);
            }
        }
    }

    const int bhb = b * H_;
    if (y == 2) {
        // stage [d_global][l_local] fp16 in LDS, then row-copy to VT
#pragma unroll
        for (int s = 0; s < 2; s++)
#pragma unroll
            for (int n = 0; n < 4; n++) {
                int dg = w * 64 + (n >> 1) * 32 + (n & 1) * 16 + c;
                int ll = s * 16 + g * 4;
                float2 pr;
                pr.x = pkrtz(acc[s][n][0], acc[s][n][1]);
                pr.y = pkrtz(acc[s][n][2], acc[s][n][3]);
                *(float2*)(ldsV + (size_t)dg * 36 + ll) = pr;
            }
        __syncthreads();
        const int t = threadIdx.x;
        const int h = t >> 5, d = t & 31;
        f16* row = vo + ((size_t)(bhb + h) * DH_ + d) * (size_t)L + lb;
#pragma unroll
        for (int j = 0; j < 8; j++)
            *(f16x4*)(row + j * 4) = *(const f16x4*)(ldsV + (size_t)t * 36 + j * 4);
    } else {
        __bf16* out = (y == 0) ? qo : ko;
#pragma unroll
        for (int s = 0; s < 2; s++)
#pragma unroll
            for (int n = 0; n < 4; n++) {
                int dlo = (n & 1) * 16 + g * 4;
                int h = w * 2 + (n >> 1);
                int l = lb + s * 16 + c;
                *(bf16x4*)(out + ((size_t)(bhb + h) * (size_t)L + l) * DH_ + dlo) = pack4(acc[s][n]);
            }
    }
}

// ---- flash attention: 64 q/wave, fp16 P (pkrtz), h-paired 16KB LDS, split-K ----
__device__ __forceinline__ void attn_step(
    const bf16x8 (&qf)[4], const bf16x8 (&kf)[4], bf16x8 (&kfN)[4],
    const __bf16* __restrict__ knext,
    const f16* __restrict__ vb0, const f16* __restrict__ vb1, int kb,
    f16* __restrict__ Pw, int g, int c,
    float (&l)[4], floatx4 (&o)[4][2])
{
    f16x8 vf[4];
    vf[0] = *(const f16x8*)(vb0 + kb);
    vf[1] = *(const f16x8*)(vb1 + kb);
    vf[2] = *(const f16x8*)(vb0 + kb + 32);
    vf[3] = *(const f16x8*)(vb1 + kb + 32);
    kfN[0] = ldb(knext);
    kfN[1] = ldb(knext + 16 * DH_);
    kfN[2] = ldb(knext + 32 * DH_);
    kfN[3] = ldb(knext + 48 * DH_);

#pragma unroll
    for (int hp = 0; hp < 2; hp++) {
#pragma unroll
        for (int hh = 0; hh < 2; hh++) {
            const int h = hp * 2 + hh;
            floatx4 s[4];
#pragma unroll
            for (int st = 0; st < 4; st++)
                s[st] = __builtin_amdgcn_mfma_f32_16x16x32_bf16(
                            kf[st], qf[h], (floatx4){0.f, 0.f, 0.f, 0.f}, 0, 0, 0);
#pragma unroll
            for (int st = 0; st < 4; st++) {
                float e0 = __builtin_amdgcn_exp2f(s[st][0]);
                float e1 = __builtin_amdgcn_exp2f(s[st][1]);
                float e2 = __builtin_amdgcn_exp2f(s[st][2]);
                float e3 = __builtin_amdgcn_exp2f(s[st][3]);
                l[h] += (e0 + e1) + (e2 + e3);
                float2 pr;
                pr.x = pkrtz(e0, e1);
                pr.y = pkrtz(e2, e3);
                *(float2*)(Pw + hh * 1024 + ((st * 2 + (g >> 1)) * 16 + c) * 8 + (g & 1) * 4) = pr;
            }
        }
        // consume both P buffers of this h-pair (wave-private: in-order DS, no barrier)
#pragma unroll
        for (int kc = 0; kc < 2; kc++)
#pragma unroll
            for (int hh = 0; hh < 2; hh++) {
                const int h = hp * 2 + hh;
                f16x8 pa = *(const f16x8*)(Pw + hh * 1024 + ((kc * 4 + g) * 16 + c) * 8);
                o[h][0] = __builtin_amdgcn_mfma_f32_16x16x32_f16(pa, vf[kc * 2 + 0], o[h][0], 0, 0, 0);
                o[h][1] = __builtin_amdgcn_mfma_f32_16x16x32_f16(pa, vf[kc * 2 + 1], o[h][1], 0, 0, 0);
            }
    }
}

template<bool DIRECT>
__global__ __launch_bounds__(256, 2) void attn_kernel(
    const __bf16* __restrict__ Q, const __bf16* __restrict__ K,
    const f16* __restrict__ VT, float* __restrict__ out,
    f16* __restrict__ Opart, float* __restrict__ Lpart, int klen, int split)
{
    __shared__ f16 ldsP[4][2][1024];   // [wave][h-parity], wave-private, 16 KB

    const int bid  = blockIdx.x;
    const int work = (bid & 7) * (32 * split) + (bid >> 3);
    const int xb   = work & 15;
    const int bh   = (work >> 4) & 15;
    const int z    = work >> 8;

    const int lane  = threadIdx.x & 63;
    const int w     = threadIdx.x >> 6;
    const int g     = lane >> 4;
    const int c     = lane & 15;
    const int qbase = xb * 256 + w * 64;
    const int k0    = z * klen;

    bf16x8 qf[4];
#pragma unroll
    for (int h = 0; h < 4; h++)
        qf[h] = ldb(Q + ((size_t)bh * L1_ + qbase + h * 16 + c) * DH_ + g * 8);

    const __bf16* kbase = K  + (size_t)bh * L2_ * DH_ + (size_t)c * DH_ + g * 8;
    const f16*    vb0   = VT + ((size_t)bh * DH_ + c)      * L2_ + g * 8;
    const f16*    vb1   = VT + ((size_t)bh * DH_ + 16 + c) * L2_ + g * 8;
    f16* Pw = &ldsP[w][0][0];

    float l[4] = {0.f, 0.f, 0.f, 0.f};
    floatx4 o[4][2];
#pragma unroll
    for (int h = 0; h < 4; h++) { o[h][0] = (floatx4){0.f,0.f,0.f,0.f}; o[h][1] = (floatx4){0.f,0.f,0.f,0.f}; }

    bf16x8 kfA[4], kfB[4];
#pragma unroll
    for (int st = 0; st < 4; st++)
        kfA[st] = ldb(kbase + (size_t)(k0 + st * 16) * DH_);

    for (int t = 0; t < klen; t += 128) {
        int kb = k0 + t;
        attn_step(qf, kfA, kfB, kbase + (size_t)(kb + 64) * DH_,
                  vb0, vb1, kb, Pw, g, c, l, o);
        int nn = (t + 128 < klen) ? kb + 128 : k0;
        attn_step(qf, kfB, kfA, kbase + (size_t)nn * DH_,
                  vb0, vb1, kb + 64, Pw, g, c, l, o);
    }

#pragma unroll
    for (int h = 0; h < 4; h++) {
        l[h] += __shfl_xor(l[h], 16, 64);
        l[h] += __shfl_xor(l[h], 32, 64);
    }

    const int b  = bh / H_;
    const int hh = bh % H_;
    if (DIRECT) {
#pragma unroll
        for (int h = 0; h < 4; h++)
#pragma unroll
            for (int r = 0; r < 4; r++) {
                float lr  = __shfl(l[h], g * 4 + r, 64);
                float inv = 1.0f / lr;
                size_t base = ((size_t)(b * L1_ + qbase + h * 16 + g * 4 + r)) * DM_ + hh * DH_;
                out[base + c]      = o[h][0][r] * inv;
                out[base + 16 + c] = o[h][1][r] * inv;
            }
    } else {
        f16* Op = Opart + (size_t)z * ((size_t)B_ * L1_ * DM_);
#pragma unroll
        for (int h = 0; h < 4; h++) {
#pragma unroll
            for (int r = 0; r < 4; r++) {
                size_t base = ((size_t)(b * L1_ + qbase + h * 16 + g * 4 + r)) * DM_ + hh * DH_;
                Op[base + c]      = (f16)o[h][0][r];
                Op[base + 16 + c] = (f16)o[h][1][r];
            }
            if (g == 0)
                Lpart[(size_t)z * ((size_t)B_ * H_ * L1_) +
                      (size_t)bh * L1_ + qbase + h * 16 + c] = l[h];
        }
    }
}

// out = (sum_z Opart) / (sum_z Lpart)
__global__ __launch_bounds__(256) void combine_kernel(
    const f16* __restrict__ Opart, const float* __restrict__ Lpart,
    float* __restrict__ out, int split)
{
    int t   = blockIdx.x * 256 + threadIdx.x;
    int row = t >> 6;
    int col = (t & 63) * 4;
    int b   = row >> 12;
    int q   = row & (L1_ - 1);
    int bh  = b * H_ + (col >> 5);
    float4 a = {0.f, 0.f, 0.f, 0.f};
    float ls = 0.f;
    for (int z = 0; z < split; z++) {
        const f16* Op = Opart + (size_t)z * ((size_t)B_ * L1_ * DM_);
        f16x4 v = *(const f16x4*)(Op + (size_t)row * DM_ + col);
        a.x += (float)v[0]; a.y += (float)v[1];
        a.z += (float)v[2]; a.w += (float)v[3];
        ls += Lpart[(size_t)z * ((size_t)B_ * H_ * L1_) + (size_t)bh * L1_ + q];
    }
    float inv = 1.0f / ls;
    float4 r; r.x = a.x * inv; r.y = a.y * inv; r.z = a.z * inv; r.w = a.w * inv;
    *(float4*)(out + (size_t)row * DM_ + col) = r;
}

extern "C" void kernel_launch(void* const* d_in, const int* in_sizes, int n_in,
                              void* d_out, int out_size, void* d_ws, size_t ws_size,
                              hipStream_t stream) {
    const float* x   = (const float*)d_in[0];
    const float* src = (const float*)d_in[1];
    const float* Wq  = (const float*)d_in[2];
    const float* Wk  = (const float*)d_in[3];
    const float* Wv  = (const float*)d_in[4];
    float* out = (float*)d_out;

    const float qscale = 1.4426950408889634f / sqrtf((float)DH_); // log2e * Dh^-0.5

    const size_t nW = 3 * 65536;
    const size_t nQ = (size_t)B_ * H_ * L1_ * DH_;   // 2,097,152
    const size_t nK = (size_t)B_ * H_ * L2_ * DH_;   // 3,145,728
    const size_t nX = nQ;

    // persistent: [W | Q | K | VT], union region: phase1 xbf/sbf, phase2 Opart/Lpart
    __bf16* wbf = (__bf16*)d_ws;
    __bf16* qws = wbf + nW;
    __bf16* kws = qws + nQ;
    f16*    vt  = (f16*)(kws + nK);
    size_t unionOff = ((nW + nQ + 2 * nK) * 2 + 255) & ~(size_t)255;
    __bf16* xbf = (__bf16*)((char*)d_ws + unionOff);
    __bf16* sbf = xbf + nX;

    const size_t oPartB = (size_t)B_ * L1_ * DM_ * sizeof(f16);   // 4 MB / split
    const size_t lPartB = (size_t)B_ * H_ * L1_ * 4;              // 256 KB / split
    const size_t avail  = ws_size > unionOff ? ws_size - unionOff : 0;
    int split = 1;
    if      (avail >= 8 * (oPartB + lPartB)) split = 8;
    else if (avail >= 6 * (oPartB + lPartB)) split = 6;
    else if (avail >= 4 * (oPartB + lPartB)) split = 4;
    else if (avail >= 2 * (oPartB + lPartB)) split = 2;
    f16*   Opart = (f16*)((char*)d_ws + unionOff);
    float* Lpart = (float*)((char*)d_ws + unionOff + (size_t)split * oPartB);

    cvt_all<<<dim3(5312), 256, 0, stream>>>(Wq, Wk, Wv, x, src, wbf, xbf, sbf, qscale);
    proj_kernel<<<dim3(1024), 256, 0, stream>>>(xbf, sbf, wbf, qws, kws, vt);

    if (split > 1) {
        attn_kernel<false><<<dim3(256 * split), 256, 0, stream>>>(
            qws, kws, vt, nullptr, Opart, Lpart, L2_ / split, split);
        combine_kernel<<<dim3(2048), 256, 0, stream>>>(Opart, Lpart, out, split);
    } else {
        attn_kernel<true><<<dim3(256), 256, 0, stream>>>(
            qws, kws, vt, out, nullptr, nullptr, L2_, 1);
    }
}